// Round 8
// baseline (369.207 us; speedup 1.0000x reference)
//
#include <hip/hip_runtime.h>

typedef __attribute__((ext_vector_type(8))) short bf8_t;   // 8 bf16 (4 VGPRs)
typedef __attribute__((ext_vector_type(4))) short s4_t;    // 4 bf16
typedef __attribute__((ext_vector_type(4))) float f4_t;    // 4 f32
typedef __attribute__((ext_vector_type(4))) unsigned u4_t; // 4 u32

#define DEV static __device__ __forceinline__

DEV short f2bf(float f) {
  union { float f; unsigned u; } x; x.f = f;
  unsigned r = x.u + 0x7FFFu + ((x.u >> 16) & 1u);   // RNE
  return (short)(r >> 16);
}
DEV float bf2f(short h) {
  union { unsigned u; float f; } x; x.u = ((unsigned)(unsigned short)h) << 16;
  return x.f;
}
DEV unsigned pk2(float a, float b) {
  return (unsigned)(unsigned short)f2bf(a) |
         ((unsigned)(unsigned short)f2bf(b) << 16);
}
DEV f4_t mfma16(bf8_t a, bf8_t b, f4_t c) {
  return __builtin_amdgcn_mfma_f32_16x16x32_bf16(a, b, c, 0, 0, 0);
}
DEV f4_t zf4() { f4_t v = {0.f, 0.f, 0.f, 0.f}; return v; }

// split f32x8 -> bf16 hi + bf16 lo
DEV void cvt8(const f4_t& f0, const f4_t& f1, bf8_t& hv, bf8_t& lv) {
#pragma unroll
  for (int i = 0; i < 4; i++) {
    short h = f2bf(f0[i]); hv[i] = h; lv[i] = f2bf(f0[i] - bf2f(h));
  }
#pragma unroll
  for (int i = 0; i < 4; i++) {
    short h = f2bf(f1[i]); hv[4 + i] = h; lv[4 + i] = f2bf(f1[i] - bf2f(h));
  }
}

// ---------------------------------------------------------------------------
// Kernel 1: fused QKV projection, FULL-K per block (no split-K partials).
// 768 blocks = 8 m-tiles(32 rows) x 96 n-tiles(64 cols over [Q|K|V]).
// Epilogue: RoPE + 1/sqrt(HD) + hi/lo split (Q) / f32 cache-layout (K,V).
// ---------------------------------------------------------------------------
__global__ __launch_bounds__(256, 3)
void qkv_kernel(const float* __restrict__ x, const float* __restrict__ kin,
                const float* __restrict__ vin, const float* __restrict__ wq,
                const float* __restrict__ wk, const float* __restrict__ wv,
                const float* __restrict__ fcos, const float* __restrict__ fsin,
                short* __restrict__ qh, short* __restrict__ ql,
                float* __restrict__ kf, float* __restrict__ vf)
{
  __shared__ short Bh[2][64][40], Bl[2][64][40];   // [buf][n][k] 20 KB

  int bid = blockIdx.x;
  int lin = (bid & 7) * 96 + (bid >> 3);           // XCD-contiguous
  int m0 = (lin & 7) * 32;
  int nglob = (lin >> 3) * 64;

  int mode; int ncol0; int N; const float* A; const float* W;
  if (nglob < 4096)      { mode = 0; A = x;   W = wq; N = 4096; ncol0 = nglob; }
  else if (nglob < 5120) { mode = 1; A = kin; W = wk; N = 1024; ncol0 = nglob - 4096; }
  else                   { mode = 2; A = vin; W = wv; N = 1024; ncol0 = nglob - 5120; }

  int tid = threadIdx.x, w = tid >> 6, l = tid & 63;
  f4_t acc[2];
#pragma unroll
  for (int i = 0; i < 2; i++) acc[i] = zf4();

  int bn = tid & 63;
  int bch = (tid >> 6) ^ ((tid >> 3) & 3);
  int bk = bch * 8;
  const float* wptr = W + ncol0 + bn;

  int n32 = (w >> 1) * 32;                 // wave's n-half
  const float* afrag = A + (m0 + (w & 1) * 16 + (l & 15)) * 4096 + (l >> 4) * 8;

  f4_t a0 = *(const f4_t*)afrag;
  f4_t a1 = *(const f4_t*)(afrag + 4);
  float brA[8], brB[8];
#pragma unroll
  for (int j = 0; j < 8; j++) brA[j] = wptr[(size_t)(bk + j) * N];
#pragma unroll
  for (int j = 0; j < 8; j++) brB[j] = wptr[(size_t)(32 + bk + j) * N];

  auto body = [&](int it, float (&br)[8], int buf) {
    {
      f4_t f0, f1;
#pragma unroll
      for (int j = 0; j < 4; j++) { f0[j] = br[j]; f1[j] = br[4 + j]; }
      bf8_t hv, lv; cvt8(f0, f1, hv, lv);
      *(bf8_t*)&Bh[buf][bn][bk] = hv;
      *(bf8_t*)&Bl[buf][bn][bk] = lv;
    }
    f4_t a0c = a0, a1c = a1;
    if (it + 1 < 128) {
      a0 = *(const f4_t*)(afrag + (it + 1) * 32);
      a1 = *(const f4_t*)(afrag + (it + 1) * 32 + 4);
    }
    if (it + 2 < 128) {
#pragma unroll
      for (int j = 0; j < 8; j++)
        br[j] = wptr[(size_t)((it + 2) * 32 + bk + j) * N];
    }
    __syncthreads();
    bf8_t ah, al; cvt8(a0c, a1c, ah, al);
    __builtin_amdgcn_s_setprio(1);
#pragma unroll
    for (int nt = 0; nt < 2; ++nt) {
      bf8_t bh = *(const bf8_t*)&Bh[buf][n32 + nt * 16 + (l & 15)][(l >> 4) * 8];
      bf8_t bl = *(const bf8_t*)&Bl[buf][n32 + nt * 16 + (l & 15)][(l >> 4) * 8];
      acc[nt] = mfma16(ah, bh, acc[nt]);
      acc[nt] = mfma16(ah, bl, acc[nt]);
      acc[nt] = mfma16(al, bh, acc[nt]);
    }
    __builtin_amdgcn_s_setprio(0);
  };

  for (int p = 0; p < 64; ++p) {
    body(2 * p,     brA, 0);
    body(2 * p + 1, brB, 1);
  }

  // epilogue: C row = m0 + (w&1)*16 + (l>>4)*4 + i, col = nglob + n32 + nt*16 + (l&15)
  int cl = l & 15, gq = l >> 4;
#pragma unroll
  for (int nt = 0; nt < 2; ++nt) {
    int col = nglob + n32 + nt * 16 + cl;
#pragma unroll
    for (int i = 0; i < 4; i++) {
      int mrow = m0 + (w & 1) * 16 + gq * 4 + i;
      int s = mrow & 15, bb = mrow >> 4;
      float val = acc[nt][i];
      if (mode == 2) {
        int cc = col - 5120; int h = cc >> 7, d = cc & 127;
        vf[(((size_t)bb * 16 + s) * 8 + h) * 128 + d] = val;
      } else {
        float other = __shfl_xor(val, 1);   // rope partner (col^1)
        int cc = (mode == 0) ? col : (col - 4096);
        int d = cc & 127, h = cc >> 7;
        float c = fcos[s * 64 + (d >> 1)], sn = fsin[s * 64 + (d >> 1)];
        float r = ((cc & 1) == 0) ? (val * c - other * sn)
                                  : (other * sn + val * c);
        if (mode == 0) {
          r *= 0.08838834764831845f;        // 1/sqrt(128)
          short hi_ = f2bf(r), lo_ = f2bf(r - bf2f(hi_));
          int idx = ((bb * 8 + (h >> 2)) * 64 + (h & 3) * 16 + s) * 128 + d;
          qh[idx] = hi_; ql[idx] = lo_;
        } else {
          kf[(((size_t)bb * 16 + s) * 8 + h) * 128 + d] = r;
        }
      }
    }
  }
}

// ---------------------------------------------------------------------------
// Kernel 2: flash attention (R6 structure + V-write XOR swizzle).
// Grid 1024 = 128 (b,g) x 8 T-splits. KVBLK=32, 16 tiles/block. LDS 23.5 KB.
// V-write bank fix: physical 16B-unit = oo ^ (tid&7)&3 (write) /
// (l>>4) ^ (dt&3) (read) — d-row stride 16*80B === 0 mod 128 made tid&7
// invisible to the bank index, collapsing writes to 4 start banks (2x floor).
// ---------------------------------------------------------------------------
__global__ __launch_bounds__(256, 3)
void attn_kernel(const float* __restrict__ ck, const float* __restrict__ cv,
                 const short* __restrict__ qhp, const short* __restrict__ qlp,
                 const float* __restrict__ kfp, const float* __restrict__ vfp,
                 const int* __restrict__ startp,
                 float* __restrict__ Op, float* __restrict__ mp,
                 float* __restrict__ lp)
{
  __shared__ short Kh[32][136];   // [t][d]  rows 272B
  __shared__ short Vt[128][40];   // [d][t]  rows 80B
  __shared__ short Ps[4][16][40]; // per-wave P [qrow][t]

  int bid = blockIdx.x;
  int bg = bid >> 3, sp = bid & 7;
  int b = bg >> 3, g = bg & 7;
  int tid = threadIdx.x, w = tid >> 6, l = tid & 63;
  int start = *startp;

  bf8_t qfh[4], qfl[4];
  {
    int qoff = (bg * 64 + w * 16 + (l & 15)) * 128 + (l >> 4) * 8;
#pragma unroll
    for (int kt = 0; kt < 4; ++kt) {
      qfh[kt] = *(const bf8_t*)(qhp + qoff + kt * 32);
      qfl[kt] = *(const bf8_t*)(qlp + qoff + kt * 32);
    }
  }
  f4_t of[8];
#pragma unroll
  for (int i = 0; i < 8; i++) of[i] = zf4();
  float mrun[4], lrun[4];
#pragma unroll
  for (int i = 0; i < 4; i++) { mrun[i] = -1e30f; lrun[i] = 0.f; }

  int st_t = tid >> 3;            // 0..31: staged t-row within tile
  int d0   = (tid & 7) * 16;      // staged d-chunk
  int rr   = (tid >> 3) & 7;      // transpose lane index within octet
  int oo   = tid >> 6;            // t-octet (== wave)
  int vunit = ((oo ^ (tid & 7)) & 3) * 8;   // swizzled physical t-unit

  f4_t kr[4], vr[4];              // in-flight staging registers

  auto ISSUE = [&](int tile) {
    int t = sp * 512 + tile * 32 + st_t;
    size_t o_st = (((size_t)b * 4096 + t) * 8 + g) * 128;
    size_t o_fr = (((size_t)b * 16 + (size_t)(t - start)) * 8 + g) * 128;
    const float* kp_ = (t < start) ? (ck + o_st) : (kfp + o_fr);
    const float* vp_ = (t < start) ? (cv + o_st) : (vfp + o_fr);
#pragma unroll
    for (int j = 0; j < 4; j++) kr[j] = *(const f4_t*)(kp_ + d0 + 4 * j);
#pragma unroll
    for (int j = 0; j < 4; j++) vr[j] = *(const f4_t*)(vp_ + d0 + 4 * j);
  };

  auto WRITE = [&]() {
    // K: pack 16 d-values -> 8 u32, two b128 writes (at the b128 floor)
    unsigned kp[8];
#pragma unroll
    for (int p = 0; p < 8; p++)
      kp[p] = pk2(kr[p >> 1][(p & 1) * 2], kr[p >> 1][(p & 1) * 2 + 1]);
    u4_t kw0 = {kp[0], kp[1], kp[2], kp[3]};
    u4_t kw1 = {kp[4], kp[5], kp[6], kp[7]};
    *(u4_t*)&Kh[st_t][d0] = kw0;
    *(u4_t*)&Kh[st_t][d0 + 8] = kw1;

    // V: pack + 8x8 u32 butterfly transpose across lanes, b128 row-writes
    unsigned vp[8];
#pragma unroll
    for (int p = 0; p < 8; p++)
      vp[p] = pk2(vr[p >> 1][(p & 1) * 2], vr[p >> 1][(p & 1) * 2 + 1]);
#pragma unroll
    for (int kk = 1; kk < 8; kk <<= 1) {
      unsigned nv[8];
#pragma unroll
      for (int i = 0; i < 8; i++) {
        unsigned ex = __shfl_xor(vp[i ^ kk], kk * 8);
        bool swp = (((i & kk) != 0) != ((rr & kk) != 0));
        nv[i] = swp ? ex : vp[i];
      }
#pragma unroll
      for (int i = 0; i < 8; i++) vp[i] = nv[i];
    }
    u4_t ra, rb;
#pragma unroll
    for (int i = 0; i < 4; i++) {
      ra[i] = (vp[2 * i] & 0xffffu) | (vp[2 * i + 1] << 16);
      rb[i] = (vp[2 * i] >> 16) | (vp[2 * i + 1] & 0xffff0000u);
    }
    *(u4_t*)&Vt[d0 + 2 * rr][vunit] = ra;
    *(u4_t*)&Vt[d0 + 2 * rr + 1][vunit] = rb;
  };

  ISSUE(0);
  WRITE();
  __syncthreads();
  ISSUE(1);

  for (int tile = 0; tile < 16; ++tile) {
    // ---- compute on staged tile ----
    f4_t sf[2];
#pragma unroll
    for (int i = 0; i < 2; i++) sf[i] = zf4();
    __builtin_amdgcn_s_setprio(1);
#pragma unroll
    for (int tt = 0; tt < 2; ++tt)
#pragma unroll
      for (int kt = 0; kt < 4; ++kt) {
        bf8_t kb = *(const bf8_t*)&Kh[tt * 16 + (l & 15)][kt * 32 + (l >> 4) * 8];
        sf[tt] = mfma16(qfh[kt], kb, sf[tt]);
        sf[tt] = mfma16(qfl[kt], kb, sf[tt]);
      }
    __builtin_amdgcn_s_setprio(0);

    float mt[4];
#pragma unroll
    for (int i = 0; i < 4; i++) mt[i] = fmaxf(sf[0][i], sf[1][i]);
#pragma unroll
    for (int st = 1; st < 16; st <<= 1)
#pragma unroll
      for (int i = 0; i < 4; i++) mt[i] = fmaxf(mt[i], __shfl_xor(mt[i], st));
    float sc[4];
#pragma unroll
    for (int i = 0; i < 4; i++) {
      float mn = fmaxf(mrun[i], mt[i]);
      sc[i] = __expf(mrun[i] - mn);
      mrun[i] = mn;
    }
    float rs[4] = {0.f, 0.f, 0.f, 0.f};
#pragma unroll
    for (int tt = 0; tt < 2; ++tt)
#pragma unroll
      for (int i = 0; i < 4; i++) {
        float pexp = __expf(sf[tt][i] - mrun[i]);
        rs[i] += pexp;
        Ps[w][(l >> 4) * 4 + i][tt * 16 + (l & 15)] = f2bf(pexp);
      }
#pragma unroll
    for (int st = 1; st < 16; st <<= 1)
#pragma unroll
      for (int i = 0; i < 4; i++) rs[i] += __shfl_xor(rs[i], st);
#pragma unroll
    for (int i = 0; i < 4; i++) lrun[i] = lrun[i] * sc[i] + rs[i];
#pragma unroll
    for (int dt = 0; dt < 8; ++dt)
#pragma unroll
      for (int i = 0; i < 4; i++) of[dt][i] *= sc[i];

    __builtin_amdgcn_s_setprio(1);
    {
      bf8_t pa = *(const bf8_t*)&Ps[w][l & 15][(l >> 4) * 8];
#pragma unroll
      for (int dt = 0; dt < 8; ++dt) {
        bf8_t vfr = *(const bf8_t*)&Vt[dt * 16 + (l & 15)][(((l >> 4) ^ dt) & 3) * 8];
        of[dt] = mfma16(pa, vfr, of[dt]);
      }
    }
    __builtin_amdgcn_s_setprio(0);

    // ---- stage tile+1 into LDS; issue tile+2 ----
    if (tile < 15) {
      __syncthreads();
      WRITE();
      __syncthreads();
      if (tile < 14) ISSUE(tile + 2);
    }
  }

  size_t obase = ((size_t)(bg * 8 + sp) * 64 + w * 16) * 128;
#pragma unroll
  for (int dt = 0; dt < 8; ++dt)
#pragma unroll
    for (int i = 0; i < 4; i++)
      Op[obase + ((l >> 4) * 4 + i) * 128 + dt * 16 + (l & 15)] = of[dt][i];
  if ((l & 15) == 0) {
    int rbase = (bg * 8 + sp) * 64 + w * 16 + (l >> 4) * 4;
#pragma unroll
    for (int i = 0; i < 4; i++) { mp[rbase + i] = mrun[i]; lp[rbase + i] = lrun[i]; }
  }
}

// ---------------------------------------------------------------------------
// Kernel 3: merge the 8 softmax partials -> bf16 attn-out (256 x 4096)
// ---------------------------------------------------------------------------
__global__ __launch_bounds__(256)
void merge_kernel(const float* __restrict__ Op, const float* __restrict__ mp,
                  const float* __restrict__ lp, short* __restrict__ attnb)
{
  int bg = blockIdx.x;
  int tid = threadIdx.x;
  int row = tid >> 2, dc = (tid & 3) * 32;
  int b = bg >> 3, g = bg & 7;
  int r = row >> 4, s = row & 15;
  float mm[8], ww[8];
  float M = -1e30f;
#pragma unroll
  for (int spp = 0; spp < 8; ++spp) {
    mm[spp] = mp[(bg * 8 + spp) * 64 + row];
    M = fmaxf(M, mm[spp]);
  }
  float denom = 0.f;
#pragma unroll
  for (int spp = 0; spp < 8; ++spp) {
    ww[spp] = __expf(mm[spp] - M);
    denom += lp[(bg * 8 + spp) * 64 + row] * ww[spp];
  }
  float inv = 1.0f / denom;
  int ob = (b * 16 + s) * 4096 + (g * 4 + r) * 128 + dc;
#pragma unroll
  for (int j = 0; j < 8; j++) {
    f4_t a = zf4();
#pragma unroll
    for (int spp = 0; spp < 8; ++spp) {
      f4_t o = *(const f4_t*)(Op + ((size_t)(bg * 8 + spp) * 64 + row) * 128 + dc + j * 4);
#pragma unroll
      for (int i = 0; i < 4; i++) a[i] += ww[spp] * o[i];
    }
    s4_t o4;
#pragma unroll
    for (int i = 0; i < 4; i++) o4[i] = f2bf(a[i] * inv);
    *(s4_t*)(attnb + ob + j * 4) = o4;
  }
}

// ---------------------------------------------------------------------------
// Kernel 4: output projection, FULL-K per block, writes f32 out directly.
// 512 blocks = 8 m-tiles(32) x 64 n-tiles(64).
// ---------------------------------------------------------------------------
__global__ __launch_bounds__(256, 3)
void wo_kernel(const short* __restrict__ attnb, const float* __restrict__ wo,
               float* __restrict__ out)
{
  __shared__ short Bs[2][64][40];   // 10 KB

  int bid = blockIdx.x;
  int lin = (bid & 7) * 64 + (bid >> 3);
  int m0 = (lin & 7) * 32, n0 = (lin >> 3) * 64;

  int tid = threadIdx.x, w = tid >> 6, l = tid & 63;
  f4_t acc[2];
#pragma unroll
  for (int i = 0; i < 2; i++) acc[i] = zf4();

  int bn = tid & 63;
  int bch = (tid >> 6) ^ ((tid >> 3) & 3);
  int bk = bch * 8;
  const float* wptr = wo + n0 + bn;
  int n32 = (w >> 1) * 32;
  const short* afrag = attnb + (m0 + (w & 1) * 16 + (l & 15)) * 4096 + (l >> 4) * 8;

  bf8_t areg = *(const bf8_t*)afrag;
  float brA[8], brB[8];
#pragma unroll
  for (int j = 0; j < 8; j++) brA[j] = wptr[(size_t)(bk + j) * 4096];
#pragma unroll
  for (int j = 0; j < 8; j++) brB[j] = wptr[(size_t)(32 + bk + j) * 4096];

  auto body = [&](int it, float (&br)[8], int buf) {
    {
      bf8_t hv;
#pragma unroll
      for (int j = 0; j < 8; j++) hv[j] = f2bf(br[j]);
      *(bf8_t*)&Bs[buf][bn][bk] = hv;
    }
    bf8_t ac = areg;
    if (it + 1 < 128) areg = *(const bf8_t*)(afrag + (it + 1) * 32);
    if (it + 2 < 128) {
#pragma unroll
      for (int j = 0; j < 8; j++)
        br[j] = wptr[(size_t)((it + 2) * 32 + bk + j) * 4096];
    }
    __syncthreads();
    __builtin_amdgcn_s_setprio(1);
#pragma unroll
    for (int nt = 0; nt < 2; ++nt) {
      bf8_t bb_ = *(const bf8_t*)&Bs[buf][n32 + nt * 16 + (l & 15)][(l >> 4) * 8];
      acc[nt] = mfma16(ac, bb_, acc[nt]);
    }
    __builtin_amdgcn_s_setprio(0);
  };

  for (int p = 0; p < 64; ++p) {
    body(2 * p,     brA, 0);
    body(2 * p + 1, brB, 1);
  }

  int cl = l & 15, gq = l >> 4;
#pragma unroll
  for (int nt = 0; nt < 2; ++nt)
#pragma unroll
    for (int i = 0; i < 4; i++)
      out[(m0 + (w & 1) * 16 + gq * 4 + i) * 4096 + n0 + n32 + nt * 16 + cl] =
          acc[nt][i];
}

// ---------------------------------------------------------------------------
extern "C" void kernel_launch(void* const* d_in, const int* in_sizes, int n_in,
                              void* d_out, int out_size, void* d_ws, size_t ws_size,
                              hipStream_t stream)
{
  const float* x  = (const float*)d_in[0];
  const float* k  = (const float*)d_in[1];
  const float* v  = (const float*)d_in[2];
  const float* wq = (const float*)d_in[3];
  const float* wk = (const float*)d_in[4];
  const float* wv = (const float*)d_in[5];
  const float* wo = (const float*)d_in[6];
  const float* ck = (const float*)d_in[7];
  const float* cv = (const float*)d_in[8];
  const float* fc = (const float*)d_in[9];
  const float* fs = (const float*)d_in[10];
  const int*   spv = (const int*)d_in[11];
  float* out = (float*)d_out;

  char* p = (char*)d_ws;
  float* Op = (float*)p; p += (size_t)1024 * 64 * 128 * 4;   // 33.6 MB
  short* qh = (short*)p; p += (size_t)128 * 64 * 128 * 2;    // 2 MB
  short* ql = (short*)p; p += (size_t)128 * 64 * 128 * 2;    // 2 MB
  float* kf = (float*)p; p += (size_t)256 * 8 * 128 * 4;     // 1 MB
  float* vf = (float*)p; p += (size_t)256 * 8 * 128 * 4;     // 1 MB
  short* attnb = (short*)p; p += (size_t)256 * 4096 * 2;     // 2 MB
  float* mp = (float*)p; p += (size_t)1024 * 64 * 4;
  float* lp = (float*)p; p += (size_t)1024 * 64 * 4;

  hipLaunchKernelGGL(qkv_kernel, dim3(768), dim3(256), 0, stream,
                     x, k, v, wq, wk, wv, fc, fs, qh, ql, kf, vf);
  hipLaunchKernelGGL(attn_kernel, dim3(1024), dim3(256), 0, stream,
                     ck, cv, qh, ql, kf, vf, spv, Op, mp, lp);
  hipLaunchKernelGGL(merge_kernel, dim3(128), dim3(256), 0, stream,
                     Op, mp, lp, attnb);
  hipLaunchKernelGGL(wo_kernel, dim3(512), dim3(256), 0, stream,
                     attnb, wo, out);
}

// Round 9
// 288.197 us; speedup vs baseline: 1.2811x; 1.2811x over previous
//
#include <hip/hip_runtime.h>

typedef __attribute__((ext_vector_type(8))) short bf8_t;   // 8 bf16 (4 VGPRs)
typedef __attribute__((ext_vector_type(4))) short s4_t;    // 4 bf16
typedef __attribute__((ext_vector_type(4))) float f4_t;    // 4 f32
typedef __attribute__((ext_vector_type(4))) unsigned u4_t; // 4 u32

#define DEV static __device__ __forceinline__

DEV short f2bf(float f) {
  union { float f; unsigned u; } x; x.f = f;
  unsigned r = x.u + 0x7FFFu + ((x.u >> 16) & 1u);   // RNE
  return (short)(r >> 16);
}
DEV float bf2f(short h) {
  union { unsigned u; float f; } x; x.u = ((unsigned)(unsigned short)h) << 16;
  return x.f;
}
DEV unsigned pk2(float a, float b) {
  return (unsigned)(unsigned short)f2bf(a) |
         ((unsigned)(unsigned short)f2bf(b) << 16);
}
DEV f4_t mfma16(bf8_t a, bf8_t b, f4_t c) {
  return __builtin_amdgcn_mfma_f32_16x16x32_bf16(a, b, c, 0, 0, 0);
}
DEV f4_t zf4() { f4_t v = {0.f, 0.f, 0.f, 0.f}; return v; }

// ---------------------------------------------------------------------------
// Kernel 0: convert x,k,v (f32) -> bf16 once (kills per-use A conversions).
// 3 x 1048576 elems, 8 per thread -> 1536 blocks.
// ---------------------------------------------------------------------------
__global__ __launch_bounds__(256)
void prep_inputs(const float* __restrict__ x, const float* __restrict__ k,
                 const float* __restrict__ v, short* __restrict__ xb,
                 short* __restrict__ kb, short* __restrict__ vb)
{
  int gid = blockIdx.x * 256 + threadIdx.x;
  size_t base = (size_t)gid * 8;
  const float* src; short* dst; size_t off;
  if (base < 1048576)       { src = x; dst = xb; off = base; }
  else if (base < 2097152)  { src = k; dst = kb; off = base - 1048576; }
  else                      { src = v; dst = vb; off = base - 2097152; }
  f4_t f0 = *(const f4_t*)(src + off);
  f4_t f1 = *(const f4_t*)(src + off + 4);
  bf8_t hv;
#pragma unroll
  for (int j = 0; j < 4; j++) { hv[j] = f2bf(f0[j]); hv[4 + j] = f2bf(f1[j]); }
  *(bf8_t*)(dst + off) = hv;
}

// ---------------------------------------------------------------------------
// Kernel 1: QKV projection, split-K=4, plain bf16 (1 MFMA stream).
// Grid 1536 = 4 ksplits x (4m x 96n tiles of 64x64). A bf16 direct from L2;
// B f32 -> bf16(hi) cvt in-loop, dbuf LDS. Output f32 partials [4][256][6144].
// ---------------------------------------------------------------------------
__global__ __launch_bounds__(256, 4)
void qkv_kernel(const short* __restrict__ xb, const short* __restrict__ kb,
                const short* __restrict__ vb, const float* __restrict__ wq,
                const float* __restrict__ wk, const float* __restrict__ wv,
                float* __restrict__ part)
{
  __shared__ short Bs[2][64][40];   // [buf][n][k] 10 KB

  int bid = blockIdx.x;
  int sw = (bid & 7) * 192 + (bid >> 3);           // XCD-contiguous
  int ks = sw / 384;
  int r  = sw % 384;

  int lin, N, cbase;
  const short* A; const float* W;
  if (r < 256)      { lin = r;       A = xb; W = wq; N = 4096; cbase = 0; }
  else if (r < 320) { lin = r - 256; A = kb; W = wk; N = 1024; cbase = 4096; }
  else              { lin = r - 320; A = vb; W = wv; N = 1024; cbase = 5120; }
  int m0 = (lin & 3) * 64;
  int n0 = (lin >> 2) * 64;
  int k0 = ks * 1024;

  int tid = threadIdx.x, w = tid >> 6, l = tid & 63;
  f4_t acc[4];
#pragma unroll
  for (int i = 0; i < 4; i++) acc[i] = zf4();

  int bn = tid & 63;
  int bch = (tid >> 6) ^ ((tid >> 3) & 3);
  int bk = bch * 8;
  const float* wptr = W + n0 + bn;

  const short* afrag = A + (m0 + w * 16 + (l & 15)) * 4096 + k0 + (l >> 4) * 8;

  bf8_t areg = *(const bf8_t*)afrag;
  float brA[8], brB[8];
#pragma unroll
  for (int j = 0; j < 8; j++) brA[j] = wptr[(size_t)(k0 + bk + j) * N];
#pragma unroll
  for (int j = 0; j < 8; j++) brB[j] = wptr[(size_t)(k0 + 32 + bk + j) * N];

  auto body = [&](int it, float (&br)[8], int buf) {
    {   // hi-only convert + b128 LDS write
      bf8_t hv;
#pragma unroll
      for (int j = 0; j < 8; j++) hv[j] = f2bf(br[j]);
      *(bf8_t*)&Bs[buf][bn][bk] = hv;
    }
    bf8_t ac = areg;
    if (it + 1 < 32) areg = *(const bf8_t*)(afrag + (it + 1) * 32);
    if (it + 2 < 32) {
#pragma unroll
      for (int j = 0; j < 8; j++)
        br[j] = wptr[(size_t)(k0 + (it + 2) * 32 + bk + j) * N];
    }
    __syncthreads();
    __builtin_amdgcn_s_setprio(1);
#pragma unroll
    for (int nt = 0; nt < 4; ++nt) {
      bf8_t bh = *(const bf8_t*)&Bs[buf][nt * 16 + (l & 15)][(l >> 4) * 8];
      acc[nt] = mfma16(ac, bh, acc[nt]);
    }
    __builtin_amdgcn_s_setprio(0);
  };

  for (int p = 0; p < 16; ++p) {
    body(2 * p,     brA, 0);
    body(2 * p + 1, brB, 1);
  }

  float* po = part + ((size_t)ks * 256 + m0) * 6144 + cbase + n0;
  int cl = l & 15, gq = l >> 4;
#pragma unroll
  for (int nt = 0; nt < 4; ++nt)
#pragma unroll
    for (int i = 0; i < 4; i++)
      po[(w * 16 + gq * 4 + i) * 6144 + nt * 16 + cl] = acc[nt][i];
}

// ---------------------------------------------------------------------------
// Kernel 2: sum 4 partials + RoPE. Q -> bf16 (MFMA layout, 1/sqrt(HD));
// K,V fresh rows -> f32 in cache layout (attn has ONE load path).
// ---------------------------------------------------------------------------
__global__ __launch_bounds__(256)
void reduce_rope(const float* __restrict__ part,
                 const float* __restrict__ fcos, const float* __restrict__ fsin,
                 short* __restrict__ qh,
                 float* __restrict__ kf, float* __restrict__ vf)
{
  int gid = blockIdx.x * 256 + threadIdx.x;
  int row = gid / 768;
  int c8  = (gid - row * 768) * 8;
  const float* p = part + (size_t)row * 6144 + c8;
  float v[8];
#pragma unroll
  for (int j = 0; j < 8; j++) v[j] = p[j];
#pragma unroll
  for (int ksp = 1; ksp < 4; ksp++) {
    const float* q = p + (size_t)ksp * 256 * 6144;
#pragma unroll
    for (int j = 0; j < 8; j++) v[j] += q[j];
  }
  int s = row & 15, bb = row >> 4;
  if (c8 < 4096) {
    int h = c8 >> 7, d = c8 & 127;
    f4_t c  = *(const f4_t*)(fcos + s * 64 + (d >> 1));
    f4_t sn = *(const f4_t*)(fsin + s * 64 + (d >> 1));
    bf8_t hv;
#pragma unroll
    for (int pr = 0; pr < 4; pr++) {
      float x0 = v[2 * pr], x1 = v[2 * pr + 1];
      float r0 = (x0 * c[pr] - x1 * sn[pr]) * 0.08838834764831845f;
      float r1 = (x0 * sn[pr] + x1 * c[pr]) * 0.08838834764831845f;
      hv[2 * pr]     = f2bf(r0);
      hv[2 * pr + 1] = f2bf(r1);
    }
    int idx = ((bb * 8 + (h >> 2)) * 64 + (h & 3) * 16 + s) * 128 + d;
    *(bf8_t*)(qh + idx) = hv;
  } else if (c8 < 5120) {
    int cc = c8 - 4096; int h = cc >> 7, d = cc & 127;
    f4_t c  = *(const f4_t*)(fcos + s * 64 + (d >> 1));
    f4_t sn = *(const f4_t*)(fsin + s * 64 + (d >> 1));
    f4_t o0, o1;
#pragma unroll
    for (int pr = 0; pr < 2; pr++) {
      float x0 = v[2 * pr], x1 = v[2 * pr + 1];
      o0[2 * pr]     = x0 * c[pr] - x1 * sn[pr];
      o0[2 * pr + 1] = x0 * sn[pr] + x1 * c[pr];
    }
#pragma unroll
    for (int pr = 2; pr < 4; pr++) {
      float x0 = v[2 * pr], x1 = v[2 * pr + 1];
      o1[2 * (pr - 2)]     = x0 * c[pr] - x1 * sn[pr];
      o1[2 * (pr - 2) + 1] = x0 * sn[pr] + x1 * c[pr];
    }
    size_t idx = (((size_t)bb * 16 + s) * 8 + h) * 128 + d;
    *(f4_t*)(kf + idx) = o0;
    *(f4_t*)(kf + idx + 4) = o1;
  } else {
    int cc = c8 - 5120; int h = cc >> 7, d = cc & 127;
    size_t idx = (((size_t)bb * 16 + s) * 8 + h) * 128 + d;
    f4_t o0, o1;
#pragma unroll
    for (int j = 0; j < 4; j++) { o0[j] = v[j]; o1[j] = v[4 + j]; }
    *(f4_t*)(vf + idx) = o0;
    *(f4_t*)(vf + idx + 4) = o1;
  }
}

// ---------------------------------------------------------------------------
// Kernel 3: flash attention (R8 structure, Q bf16 single-stream).
// Grid 1024 = 128 (b,g) x 8 T-splits. KVBLK=32, 16 tiles/block. LDS 23.5 KB.
// ---------------------------------------------------------------------------
__global__ __launch_bounds__(256, 3)
void attn_kernel(const float* __restrict__ ck, const float* __restrict__ cv,
                 const short* __restrict__ qhp,
                 const float* __restrict__ kfp, const float* __restrict__ vfp,
                 const int* __restrict__ startp,
                 float* __restrict__ Op, float* __restrict__ mp,
                 float* __restrict__ lp)
{
  __shared__ short Kh[32][136];   // [t][d]  rows 272B
  __shared__ short Vt[128][40];   // [d][t]  rows 80B
  __shared__ short Ps[4][16][40]; // per-wave P [qrow][t]

  int bid = blockIdx.x;
  int bg = bid >> 3, sp = bid & 7;
  int b = bg >> 3, g = bg & 7;
  int tid = threadIdx.x, w = tid >> 6, l = tid & 63;
  int start = *startp;

  bf8_t qfh[4];
  {
    int qoff = (bg * 64 + w * 16 + (l & 15)) * 128 + (l >> 4) * 8;
#pragma unroll
    for (int kt = 0; kt < 4; ++kt)
      qfh[kt] = *(const bf8_t*)(qhp + qoff + kt * 32);
  }
  f4_t of[8];
#pragma unroll
  for (int i = 0; i < 8; i++) of[i] = zf4();
  float mrun[4], lrun[4];
#pragma unroll
  for (int i = 0; i < 4; i++) { mrun[i] = -1e30f; lrun[i] = 0.f; }

  int st_t = tid >> 3;            // 0..31: staged t-row within tile
  int d0   = (tid & 7) * 16;      // staged d-chunk
  int rr   = (tid >> 3) & 7;      // transpose lane index within octet
  int oo   = tid >> 6;            // t-octet (== wave)
  int vunit = ((oo ^ (tid & 7)) & 3) * 8;   // swizzled physical t-unit

  f4_t kr[4], vr[4];              // in-flight staging registers

  auto ISSUE = [&](int tile) {
    int t = sp * 512 + tile * 32 + st_t;
    size_t o_st = (((size_t)b * 4096 + t) * 8 + g) * 128;
    size_t o_fr = (((size_t)b * 16 + (size_t)(t - start)) * 8 + g) * 128;
    const float* kp_ = (t < start) ? (ck + o_st) : (kfp + o_fr);
    const float* vp_ = (t < start) ? (cv + o_st) : (vfp + o_fr);
#pragma unroll
    for (int j = 0; j < 4; j++) kr[j] = *(const f4_t*)(kp_ + d0 + 4 * j);
#pragma unroll
    for (int j = 0; j < 4; j++) vr[j] = *(const f4_t*)(vp_ + d0 + 4 * j);
  };

  auto WRITE = [&]() {
    // K: pack 16 d-values -> 8 u32, two b128 writes
    unsigned kp[8];
#pragma unroll
    for (int p = 0; p < 8; p++)
      kp[p] = pk2(kr[p >> 1][(p & 1) * 2], kr[p >> 1][(p & 1) * 2 + 1]);
    u4_t kw0 = {kp[0], kp[1], kp[2], kp[3]};
    u4_t kw1 = {kp[4], kp[5], kp[6], kp[7]};
    *(u4_t*)&Kh[st_t][d0] = kw0;
    *(u4_t*)&Kh[st_t][d0 + 8] = kw1;

    // V: pack + 8x8 u32 butterfly transpose across lanes, b128 row-writes
    unsigned vp[8];
#pragma unroll
    for (int p = 0; p < 8; p++)
      vp[p] = pk2(vr[p >> 1][(p & 1) * 2], vr[p >> 1][(p & 1) * 2 + 1]);
#pragma unroll
    for (int kk = 1; kk < 8; kk <<= 1) {
      unsigned nv[8];
#pragma unroll
      for (int i = 0; i < 8; i++) {
        unsigned ex = __shfl_xor(vp[i ^ kk], kk * 8);
        bool swp = (((i & kk) != 0) != ((rr & kk) != 0));
        nv[i] = swp ? ex : vp[i];
      }
#pragma unroll
      for (int i = 0; i < 8; i++) vp[i] = nv[i];
    }
    u4_t ra, rb;
#pragma unroll
    for (int i = 0; i < 4; i++) {
      ra[i] = (vp[2 * i] & 0xffffu) | (vp[2 * i + 1] << 16);
      rb[i] = (vp[2 * i] >> 16) | (vp[2 * i + 1] & 0xffff0000u);
    }
    *(u4_t*)&Vt[d0 + 2 * rr][vunit] = ra;
    *(u4_t*)&Vt[d0 + 2 * rr + 1][vunit] = rb;
  };

  ISSUE(0);
  WRITE();
  __syncthreads();
  ISSUE(1);

  for (int tile = 0; tile < 16; ++tile) {
    // ---- compute on staged tile ----
    f4_t sf[2];
#pragma unroll
    for (int i = 0; i < 2; i++) sf[i] = zf4();
    __builtin_amdgcn_s_setprio(1);
#pragma unroll
    for (int tt = 0; tt < 2; ++tt)
#pragma unroll
      for (int kt = 0; kt < 4; ++kt) {
        bf8_t kb = *(const bf8_t*)&Kh[tt * 16 + (l & 15)][kt * 32 + (l >> 4) * 8];
        sf[tt] = mfma16(qfh[kt], kb, sf[tt]);
      }
    __builtin_amdgcn_s_setprio(0);

    float mt[4];
#pragma unroll
    for (int i = 0; i < 4; i++) mt[i] = fmaxf(sf[0][i], sf[1][i]);
#pragma unroll
    for (int st = 1; st < 16; st <<= 1)
#pragma unroll
      for (int i = 0; i < 4; i++) mt[i] = fmaxf(mt[i], __shfl_xor(mt[i], st));
    float sc[4];
#pragma unroll
    for (int i = 0; i < 4; i++) {
      float mn = fmaxf(mrun[i], mt[i]);
      sc[i] = __expf(mrun[i] - mn);
      mrun[i] = mn;
    }
    float rs[4] = {0.f, 0.f, 0.f, 0.f};
#pragma unroll
    for (int tt = 0; tt < 2; ++tt)
#pragma unroll
      for (int i = 0; i < 4; i++) {
        float pexp = __expf(sf[tt][i] - mrun[i]);
        rs[i] += pexp;
        Ps[w][(l >> 4) * 4 + i][tt * 16 + (l & 15)] = f2bf(pexp);
      }
#pragma unroll
    for (int st = 1; st < 16; st <<= 1)
#pragma unroll
      for (int i = 0; i < 4; i++) rs[i] += __shfl_xor(rs[i], st);
#pragma unroll
    for (int i = 0; i < 4; i++) lrun[i] = lrun[i] * sc[i] + rs[i];
#pragma unroll
    for (int dt = 0; dt < 8; ++dt)
#pragma unroll
      for (int i = 0; i < 4; i++) of[dt][i] *= sc[i];

    __builtin_amdgcn_s_setprio(1);
    {
      bf8_t pa = *(const bf8_t*)&Ps[w][l & 15][(l >> 4) * 8];
#pragma unroll
      for (int dt = 0; dt < 8; ++dt) {
        bf8_t vfr = *(const bf8_t*)&Vt[dt * 16 + (l & 15)][(((l >> 4) ^ dt) & 3) * 8];
        of[dt] = mfma16(pa, vfr, of[dt]);
      }
    }
    __builtin_amdgcn_s_setprio(0);

    // ---- stage tile+1 into LDS; issue tile+2 ----
    if (tile < 15) {
      __syncthreads();
      WRITE();
      __syncthreads();
      if (tile < 14) ISSUE(tile + 2);
    }
  }

  size_t obase = ((size_t)(bg * 8 + sp) * 64 + w * 16) * 128;
#pragma unroll
  for (int dt = 0; dt < 8; ++dt)
#pragma unroll
    for (int i = 0; i < 4; i++)
      Op[obase + ((l >> 4) * 4 + i) * 128 + dt * 16 + (l & 15)] = of[dt][i];
  if ((l & 15) == 0) {
    int rbase = (bg * 8 + sp) * 64 + w * 16 + (l >> 4) * 4;
#pragma unroll
    for (int i = 0; i < 4; i++) { mp[rbase + i] = mrun[i]; lp[rbase + i] = lrun[i]; }
  }
}

// ---------------------------------------------------------------------------
// Kernel 4: merge the 8 softmax partials -> bf16 attn-out (256 x 4096).
// Grid 512 = 128 bg x 4 row-quarters (parallelism fix: was 128 blocks).
// ---------------------------------------------------------------------------
__global__ __launch_bounds__(256)
void merge_kernel(const float* __restrict__ Op, const float* __restrict__ mp,
                  const float* __restrict__ lp, short* __restrict__ attnb)
{
  int bid = blockIdx.x;
  int bg = bid >> 2, q4 = bid & 3;
  int tid = threadIdx.x;
  int row = q4 * 16 + (tid >> 4);      // 0..63 within bg
  int dc = (tid & 15) * 8;
  int b = bg >> 3, g = bg & 7;
  int r = row >> 4, s = row & 15;
  float mm[8], ww[8];
  float M = -1e30f;
#pragma unroll
  for (int spp = 0; spp < 8; ++spp) {
    mm[spp] = mp[(bg * 8 + spp) * 64 + row];
    M = fmaxf(M, mm[spp]);
  }
  float denom = 0.f;
#pragma unroll
  for (int spp = 0; spp < 8; ++spp) {
    ww[spp] = __expf(mm[spp] - M);
    denom += lp[(bg * 8 + spp) * 64 + row] * ww[spp];
  }
  float inv = 1.0f / denom;
  f4_t a0 = zf4(), a1 = zf4();
#pragma unroll
  for (int spp = 0; spp < 8; ++spp) {
    const float* o = Op + ((size_t)(bg * 8 + spp) * 64 + row) * 128 + dc;
    f4_t x0 = *(const f4_t*)o;
    f4_t x1 = *(const f4_t*)(o + 4);
#pragma unroll
    for (int i = 0; i < 4; i++) { a0[i] += ww[spp] * x0[i]; a1[i] += ww[spp] * x1[i]; }
  }
  int ob = (b * 16 + s) * 4096 + (g * 4 + r) * 128 + dc;
  bf8_t o8;
#pragma unroll
  for (int i = 0; i < 4; i++) {
    o8[i]     = f2bf(a0[i] * inv);
    o8[4 + i] = f2bf(a1[i] * inv);
  }
  *(bf8_t*)(attnb + ob) = o8;
}

// ---------------------------------------------------------------------------
// Kernel 5: output projection, FULL-K per block, writes f32 out directly.
// 512 blocks = 8 m-tiles(32) x 64 n-tiles(64). (R8 version, measured ~34us)
// ---------------------------------------------------------------------------
__global__ __launch_bounds__(256, 3)
void wo_kernel(const short* __restrict__ attnb, const float* __restrict__ wo,
               float* __restrict__ out)
{
  __shared__ short Bs[2][64][40];   // 10 KB

  int bid = blockIdx.x;
  int lin = (bid & 7) * 64 + (bid >> 3);
  int m0 = (lin & 7) * 32, n0 = (lin >> 3) * 64;

  int tid = threadIdx.x, w = tid >> 6, l = tid & 63;
  f4_t acc[2];
#pragma unroll
  for (int i = 0; i < 2; i++) acc[i] = zf4();

  int bn = tid & 63;
  int bch = (tid >> 6) ^ ((tid >> 3) & 3);
  int bk = bch * 8;
  const float* wptr = wo + n0 + bn;
  int n32 = (w >> 1) * 32;
  const short* afrag = attnb + (m0 + (w & 1) * 16 + (l & 15)) * 4096 + (l >> 4) * 8;

  bf8_t areg = *(const bf8_t*)afrag;
  float brA[8], brB[8];
#pragma unroll
  for (int j = 0; j < 8; j++) brA[j] = wptr[(size_t)(bk + j) * 4096];
#pragma unroll
  for (int j = 0; j < 8; j++) brB[j] = wptr[(size_t)(32 + bk + j) * 4096];

  auto body = [&](int it, float (&br)[8], int buf) {
    {
      bf8_t hv;
#pragma unroll
      for (int j = 0; j < 8; j++) hv[j] = f2bf(br[j]);
      *(bf8_t*)&Bs[buf][bn][bk] = hv;
    }
    bf8_t ac = areg;
    if (it + 1 < 128) areg = *(const bf8_t*)(afrag + (it + 1) * 32);
    if (it + 2 < 128) {
#pragma unroll
      for (int j = 0; j < 8; j++)
        br[j] = wptr[(size_t)((it + 2) * 32 + bk + j) * 4096];
    }
    __syncthreads();
    __builtin_amdgcn_s_setprio(1);
#pragma unroll
    for (int nt = 0; nt < 2; ++nt) {
      bf8_t bb_ = *(const bf8_t*)&Bs[buf][n32 + nt * 16 + (l & 15)][(l >> 4) * 8];
      acc[nt] = mfma16(ac, bb_, acc[nt]);
    }
    __builtin_amdgcn_s_setprio(0);
  };

  for (int p = 0; p < 64; ++p) {
    body(2 * p,     brA, 0);
    body(2 * p + 1, brB, 1);
  }

  int cl = l & 15, gq = l >> 4;
#pragma unroll
  for (int nt = 0; nt < 2; ++nt)
#pragma unroll
    for (int i = 0; i < 4; i++)
      out[(m0 + (w & 1) * 16 + gq * 4 + i) * 4096 + n0 + n32 + nt * 16 + cl] =
          acc[nt][i];
}

// ---------------------------------------------------------------------------
extern "C" void kernel_launch(void* const* d_in, const int* in_sizes, int n_in,
                              void* d_out, int out_size, void* d_ws, size_t ws_size,
                              hipStream_t stream)
{
  const float* x  = (const float*)d_in[0];
  const float* k  = (const float*)d_in[1];
  const float* v  = (const float*)d_in[2];
  const float* wq = (const float*)d_in[3];
  const float* wk = (const float*)d_in[4];
  const float* wv = (const float*)d_in[5];
  const float* wo = (const float*)d_in[6];
  const float* ck = (const float*)d_in[7];
  const float* cv = (const float*)d_in[8];
  const float* fc = (const float*)d_in[9];
  const float* fs = (const float*)d_in[10];
  const int*   spv = (const int*)d_in[11];
  float* out = (float*)d_out;

  // S region (33.6 MB) time-shared: qkv partials (25.2MB) -> Op (33.6MB).
  // Strictly sequential producers/consumers.
  char* p = (char*)d_ws;
  float* S = (float*)p; p += (size_t)1024 * 64 * 128 * 4;    // 33.6 MB
  float* qpart = S;
  float* Op    = S;
  short* xb = (short*)p; p += (size_t)256 * 4096 * 2;        // 2 MB
  short* kb = (short*)p; p += (size_t)256 * 4096 * 2;        // 2 MB
  short* vb = (short*)p; p += (size_t)256 * 4096 * 2;        // 2 MB
  short* qh = (short*)p; p += (size_t)128 * 64 * 128 * 2;    // 2 MB
  float* kf = (float*)p; p += (size_t)256 * 8 * 128 * 4;     // 1 MB
  float* vf = (float*)p; p += (size_t)256 * 8 * 128 * 4;     // 1 MB
  short* attnb = (short*)p; p += (size_t)256 * 4096 * 2;     // 2 MB
  float* mp = (float*)p; p += (size_t)1024 * 64 * 4;
  float* lp = (float*)p; p += (size_t)1024 * 64 * 4;

  hipLaunchKernelGGL(prep_inputs, dim3(1536), dim3(256), 0, stream,
                     x, k, v, xb, kb, vb);
  hipLaunchKernelGGL(qkv_kernel, dim3(1536), dim3(256), 0, stream,
                     xb, kb, vb, wq, wk, wv, qpart);
  hipLaunchKernelGGL(reduce_rope, dim3(768), dim3(256), 0, stream,
                     qpart, fc, fs, qh, kf, vf);
  hipLaunchKernelGGL(attn_kernel, dim3(1024), dim3(256), 0, stream,
                     ck, cv, qh, kf, vf, spv, Op, mp, lp);
  hipLaunchKernelGGL(merge_kernel, dim3(512), dim3(256), 0, stream,
                     Op, mp, lp, attnb);
  hipLaunchKernelGGL(wo_kernel, dim3(512), dim3(256), 0, stream,
                     attnb, wo, out);
}